// Round 12
// baseline (395.350 us; speedup 1.0000x reference)
//
#include <hip/hip_runtime.h>
#include <hip/hip_bf16.h>
#include <stdint.h>

typedef __attribute__((ext_vector_type(4))) float f32x4;
typedef __attribute__((ext_vector_type(8))) short s16x8;

__device__ __forceinline__ short f2bf(float f) {
  union { float f; uint32_t u; } v; v.f = f;
  uint32_t r = v.u + 0x7FFFu + ((v.u >> 16) & 1u);
  return (short)(r >> 16);
}
__device__ __forceinline__ uint32_t pack2bf(float a, float b) {
  return (uint32_t)(uint16_t)f2bf(a) | ((uint32_t)(uint16_t)f2bf(b) << 16);
}

__device__ __forceinline__ void async16(const void* g, void* l) {
  __builtin_amdgcn_global_load_lds(
      (const __attribute__((address_space(1))) void*)g,
      (__attribute__((address_space(3))) void*)l, 16, 0, 0);
}

// ---------------- cast x (fp32 -> bf16), 8 elems/thread ----------------
__global__ __launch_bounds__(256) void k_cast_bf16(const float* __restrict__ in,
                                                   short* __restrict__ out, int n8) {
  int i = blockIdx.x * 256 + threadIdx.x;
  if (i >= n8) return;
  const float4* p = (const float4*)in + (size_t)i * 2;
  float4 a = p[0], b = p[1];
  s16x8 o;
  o[0] = f2bf(a.x); o[1] = f2bf(a.y); o[2] = f2bf(a.z); o[3] = f2bf(a.w);
  o[4] = f2bf(b.x); o[5] = f2bf(b.y); o[6] = f2bf(b.z); o[7] = f2bf(b.w);
  ((s16x8*)out)[i] = o;
}

// -------- LDS-tiled transpose+cast: out[n][k] = bf16(in[k][n]) --------
__global__ __launch_bounds__(256) void k_transpose_cast(const float* __restrict__ in,
                                                        short* __restrict__ out,
                                                        int K, int N) {
  __shared__ float tile[64][65];
  const int bx = blockIdx.x;
  const int by = blockIdx.y;
  const int tx = threadIdx.x & 63, ty = threadIdx.x >> 6;
#pragma unroll
  for (int r = ty; r < 64; r += 4)
    tile[r][tx] = in[(size_t)(by * 64 + r) * N + bx * 64 + tx];
  __syncthreads();
#pragma unroll
  for (int r = ty; r < 64; r += 4)
    out[(size_t)(bx * 64 + r) * K + by * 64 + tx] = f2bf(tile[tx][r]);
}

// ===== persistent 256x256 bf16 GEMM — pipelined-fragment-read schedule =====
// Per K-tile, 4 phases, ONE barrier each. Phase p's MFMA consumes A-frags read
// at phase p-1 (reg sets fE/fO alternate); B-frags (bfr) read once at ph0
// (compiler emits counted lgkm wait for just those). Cross-wave publication of
// "A(s+1)/B(s+1) landed" is the vmcnt(2) at ph2 + that phase's barrier (one
// barrier BEFORE the ph3 reads that need it). Staging schedule (proven r7):
// ph0/ph1 issue A(s+1), ph2/ph3 issue B(s+2). WAR distances all >=2 barriers.
#define TILE_SH 16384  // 256*64 shorts per tile

template <int OUTMODE, int NBN, int KK>
__global__ __launch_bounds__(512, 2) void k_gemm256p(const short* __restrict__ A,
                                                     const short* __restrict__ Bw,
                                                     const float* __restrict__ bias,
                                                     void* __restrict__ C,
                                                     int N, int nrounds) {
  __shared__ short lds[2 * 2 * TILE_SH];  // 128 KiB
  const int t = threadIdx.x;
  const int w = t >> 6, l = t & 63;
  const int wm = w >> 2, wn = w & 3;
  const int swz = (((int)blockIdx.x & 7) << 5) + ((int)blockIdx.x >> 3);

  const int NT = KK >> 6;  // 8
  const int NS = nrounds * NT;

  auto stage = [&](const short* __restrict__ G, int row0, int kt, short* dst) {
#pragma unroll
    for (int L = 0; L < 2; ++L) {
      int cw = L * 512 + (t & ~63);
      int c = cw + l;
      int r = c >> 3, s = c & 7;
      async16(G + (size_t)(row0 + r) * KK + kt + ((s ^ (r & 7)) << 3), dst + cw * 8);
    }
  };
  auto issueA = [&](int step, int bmv, int hf) {
    int kt = step & 7;
    stage(A, bmv * 256 + hf * 128, kt * 64, lds + (kt & 1) * 32768 + hf * 8192);
  };
  auto issueB = [&](int step, int bnv, int hf) {
    int kt = step & 7;
    stage(Bw, bnv * 256 + hf * 128, kt * 64, lds + (kt & 1) * 32768 + TILE_SH + hf * 8192);
  };

  const int g = l >> 4, v = l & 7;
  int ofsA[2], ofsB[2];
#pragma unroll
  for (int ks = 0; ks < 2; ++ks) {
    ofsA[ks] = (wm * 128 + (l & 15)) * 64 + (((ks * 4 + g) ^ v) << 3);
    ofsB[ks] = (wn * 64 + (l & 15)) * 64 + (((ks * 4 + g) ^ v) << 3);
  }

  f32x4 acc[8][4] = {};
  s16x8 bfr[4][2];
  s16x8 fE[4], fO[4];

#define RD_A4(D, BASE, AI0)                                        \
  D[0] = *(const s16x8*)((BASE) + ofsA[0] + (AI0) * 1024);         \
  D[1] = *(const s16x8*)((BASE) + ofsA[1] + (AI0) * 1024);         \
  D[2] = *(const s16x8*)((BASE) + ofsA[0] + ((AI0) + 1) * 1024);   \
  D[3] = *(const s16x8*)((BASE) + ofsA[1] + ((AI0) + 1) * 1024);

#define RD_B8(BASE)                                                \
  _Pragma("unroll")                                                \
  for (int nj = 0; nj < 4; ++nj) {                                 \
    bfr[nj][0] = *(const s16x8*)((BASE) + ofsB[0] + nj * 1024);    \
    bfr[nj][1] = *(const s16x8*)((BASE) + ofsB[1] + nj * 1024);    \
  }

#define MFMA16(D, AI0)                                                                                          \
  __builtin_amdgcn_s_setprio(1);                                                                                \
  _Pragma("unroll")                                                                                             \
  for (int nj = 0; nj < 4; ++nj) {                                                                              \
    acc[(AI0)][nj] = __builtin_amdgcn_mfma_f32_16x16x32_bf16(D[0], bfr[nj][0], acc[(AI0)][nj], 0, 0, 0);        \
    acc[(AI0)][nj] = __builtin_amdgcn_mfma_f32_16x16x32_bf16(D[1], bfr[nj][1], acc[(AI0)][nj], 0, 0, 0);        \
    acc[(AI0) + 1][nj] = __builtin_amdgcn_mfma_f32_16x16x32_bf16(D[2], bfr[nj][0], acc[(AI0) + 1][nj], 0, 0, 0); \
    acc[(AI0) + 1][nj] = __builtin_amdgcn_mfma_f32_16x16x32_bf16(D[3], bfr[nj][1], acc[(AI0) + 1][nj], 0, 0, 0); \
  }                                                                                                             \
  __builtin_amdgcn_s_setprio(0);

  // prologue: A(0), B(0), A(1), B(1); vmcnt(8) -> A0,B0 landed; publish; read f0
  {
    const int bm0 = swz / NBN, bn0 = swz % NBN;
    issueA(0, bm0, 0); issueA(0, bm0, 1);
    issueB(0, bn0, 0); issueB(0, bn0, 1);
    issueA(1, bm0, 0); issueA(1, bm0, 1);
    issueB(1, bn0, 0); issueB(1, bn0, 1);
  }
  asm volatile("s_waitcnt vmcnt(8)" ::: "memory");
  __builtin_amdgcn_s_barrier();
  RD_A4(fE, lds, 0);

  for (int j = 0; j < nrounds; ++j) {
    const int tauc = swz + (j << 8);
    const int bmc = tauc / NBN, bnc = tauc % NBN;
    for (int T = 0; T < NT; ++T) {
      const int s = (j << 3) + T;
      const int s1 = s + 1, s2 = s + 2;
      const int tau1 = swz + ((s1 >> 3) << 8);
      const int tau2 = swz + ((s2 >> 3) << 8);
      const int bm1 = tau1 / NBN;
      const int bn2 = tau2 % NBN;
      const short* Ab = lds + (T & 1) * 32768;
      const short* Bb = Ab + TILE_SH;
      const short* Ab1 = lds + ((T + 1) & 1) * 32768;

      // ph0: bfr + f1 reads; stage A(s+1)h0; MFMA f0
      RD_B8(Bb);
      RD_A4(fO, Ab, 2);
      if (s > 0 && s1 < NS) issueA(s1, bm1, 0);
      __builtin_amdgcn_s_barrier();
      MFMA16(fE, 0);

      // ph1: f2 reads; stage A(s+1)h1; MFMA f1
      RD_A4(fE, Ab, 4);
      if (s > 0 && s1 < NS) issueA(s1, bm1, 1);
      __builtin_amdgcn_s_barrier();
      MFMA16(fO, 2);

      // ph2: f3 reads; stage B(s+2)h0; vmcnt publishes A(s+1),B(s+1) landed; MFMA f2
      RD_A4(fO, Ab, 6);
      if (s2 < NS) {
        issueB(s2, bn2, 0);
        asm volatile("s_waitcnt vmcnt(2)" ::: "memory");
      } else if (s1 < NS) {
        asm volatile("s_waitcnt vmcnt(0)" ::: "memory");
      }
      __builtin_amdgcn_s_barrier();
      MFMA16(fE, 4);

      // ph3: next-tile f0 reads (A landed, published at ph2); stage B(s+2)h1; MFMA f3
      if (s1 < NS) { RD_A4(fE, Ab1, 0); }
      if (s2 < NS) issueB(s2, bn2, 1);
      __builtin_amdgcn_s_barrier();
      MFMA16(fO, 6);
    }

    // epilogue tile j (overlaps next tile's pipeline)
#pragma unroll
    for (int ai = 0; ai < 8; ++ai)
#pragma unroll
      for (int nj = 0; nj < 4; ++nj) {
        int col = bnc * 256 + wn * 64 + nj * 16 + (l & 15);
        float bv = bias[col];
#pragma unroll
        for (int r = 0; r < 4; ++r) {
          int row = bmc * 256 + wm * 128 + ai * 16 + (l >> 4) * 4 + r;
          float vv = acc[ai][nj][r] + bv;
          if (OUTMODE == 1) {
            ((float*)C)[(size_t)row * N + col] = vv;
          } else if (OUTMODE == 0) {
            ((short*)C)[(size_t)row * N + col] = f2bf(vv);
          } else {
            int bb = row >> 6, nn = row & 63;
            int sel = col >> 9, hh = (col >> 5) & 15, dd = col & 31;
            ((short*)C)[(((size_t)(bb * 48 + hh * 3 + sel)) << 11) + (nn << 5) + dd] = f2bf(vv);
          }
        }
      }
#pragma unroll
    for (int ai = 0; ai < 8; ++ai)
#pragma unroll
      for (int nj = 0; nj < 4; ++nj)
        acc[ai][nj] = (f32x4){0.f, 0.f, 0.f, 0.f};
  }
#undef RD_A4
#undef RD_B8
#undef MFMA16
}

// ============== fused window attention v3: qkv2 layout, swapped QK^T ==============
__global__ __launch_bounds__(256) void k_attn(const short* __restrict__ qkv2,
                                              const float* __restrict__ mask,
                                              const float* __restrict__ bias_table,
                                              short* __restrict__ Y) {
  __shared__ float mask_lds[64 * 64];   // [n][m ^ ((n&7)<<2)]
  __shared__ float bias_lds[4][128];
  __shared__ short p_lds[4][64][72];
  __shared__ short v_lds[4][64][40];

  const int t = threadIdx.x, wv = t >> 6, ln = t & 63;
  const int b = blockIdx.x;
  const int h = blockIdx.y * 4 + wv;
  const int hi = ln >> 4, lo = ln & 15;

  const float4* mk = (const float4*)(mask + (size_t)(b & 63) * 4096);
#pragma unroll
  for (int u = 0; u < 4; ++u) {
    int idx = t + 256 * u;
    int row = idx >> 4, c4 = (idx & 15) * 4;
    *(float4*)&mask_lds[row * 64 + (c4 ^ ((row & 7) << 2))] = mk[idx];
  }
  for (int u = ln; u < 127; u += 64) bias_lds[wv][u] = bias_table[u * 16 + h];

  const short* base = qkv2 + ((size_t)(b * 16 + h)) * 3 * 2048;
  const short* vg = base + 4096;
#pragma unroll
  for (int u = 0; u < 4; ++u) {
    int row = u * 16 + (ln >> 2), c8 = (ln & 3) * 8;
    *(s16x8*)&v_lds[wv][row][c8] = *(const s16x8*)(vg + row * 32 + c8);
  }
  __syncthreads();

  s16x8 qf[4], kf[4];
#pragma unroll
  for (int i = 0; i < 4; ++i) {
    qf[i] = *(const s16x8*)(base + (16 * i + lo) * 32 + hi * 8);
    kf[i] = *(const s16x8*)(base + 2048 + (16 * i + lo) * 32 + hi * 8);
  }
  f32x4 s2[4][4] = {};
#pragma unroll
  for (int j = 0; j < 4; ++j)
#pragma unroll
    for (int i = 0; i < 4; ++i)
      s2[j][i] = __builtin_amdgcn_mfma_f32_16x16x32_bf16(kf[j], qf[i], s2[j][i], 0, 0, 0);

  const float scale = 0.17677669529663687f;
#pragma unroll
  for (int i = 0; i < 4; ++i) {
    const int n = 16 * i + lo;
    const int msw = (n & 7) << 2;
    float x[16];
    float vmax = -1e30f;
#pragma unroll
    for (int j = 0; j < 4; ++j)
#pragma unroll
      for (int r = 0; r < 4; ++r) {
        int m = 16 * j + 4 * hi + r;
        float xx = s2[j][i][r] * scale + bias_lds[wv][n - m + 63] +
                   mask_lds[n * 64 + (m ^ msw)];
        x[j * 4 + r] = xx;
        vmax = fmaxf(vmax, xx);
      }
    vmax = fmaxf(vmax, __shfl_xor(vmax, 16, 64));
    vmax = fmaxf(vmax, __shfl_xor(vmax, 32, 64));
    float sum = 0.f;
#pragma unroll
    for (int u = 0; u < 16; ++u) {
      x[u] = __expf(x[u] - vmax);
      sum += x[u];
    }
    sum += __shfl_xor(sum, 16, 64);
    sum += __shfl_xor(sum, 32, 64);
    float rsv = 1.0f / sum;
#pragma unroll
    for (int j = 0; j < 4; ++j)
#pragma unroll
      for (int rp = 0; rp < 2; ++rp)
        *(uint32_t*)&p_lds[wv][n][16 * j + 4 * hi + rp * 2] =
            pack2bf(x[j * 4 + rp * 2] * rsv, x[j * 4 + rp * 2 + 1] * rsv);
  }

  f32x4 o2[2][4] = {};
#pragma unroll
  for (int kk = 0; kk < 2; ++kk) {
    s16x8 pa[4];
#pragma unroll
    for (int i2 = 0; i2 < 4; ++i2)
      pa[i2] = *(const s16x8*)&p_lds[wv][16 * i2 + lo][kk * 32 + hi * 8];
#pragma unroll
    for (int j2 = 0; j2 < 2; ++j2) {
      s16x8 vf;
#pragma unroll
      for (int jj = 0; jj < 8; ++jj)
        vf[jj] = v_lds[wv][kk * 32 + hi * 8 + jj][16 * j2 + lo];
#pragma unroll
      for (int i2 = 0; i2 < 4; ++i2)
        o2[j2][i2] = __builtin_amdgcn_mfma_f32_16x16x32_bf16(vf, pa[i2], o2[j2][i2], 0, 0, 0);
    }
  }

  const int rr = h * 64 + (b >> 4);
#pragma unroll
  for (int i2 = 0; i2 < 4; ++i2) {
    int ss = (b & 15) * 4 + i2;
    short* yr = Y + ((size_t)rr * 64 + ss) * 512 + lo * 32 + 4 * hi;
#pragma unroll
    for (int j2 = 0; j2 < 2; ++j2) {
      uint2 pk;
      pk.x = pack2bf(o2[j2][i2][0], o2[j2][i2][1]);
      pk.y = pack2bf(o2[j2][i2][2], o2[j2][i2][3]);
      *(uint2*)(yr + 16 * j2) = pk;
    }
  }
}

extern "C" void kernel_launch(void* const* d_in, const int* in_sizes, int n_in,
                              void* d_out, int out_size, void* d_ws, size_t ws_size,
                              hipStream_t stream) {
  const float* x      = (const float*)d_in[0];
  const float* mask   = (const float*)d_in[1];
  const float* qkv_w  = (const float*)d_in[2];
  const float* qkv_b  = (const float*)d_in[3];
  const float* proj_w = (const float*)d_in[4];
  const float* proj_b = (const float*)d_in[5];
  const float* btab   = (const float*)d_in[6];
  float* out = (float*)d_out;

  char* w = (char*)d_ws;
  short* qkv_ws = (short*)w;                                             // 192 MiB
  short* xbf    = (short*)(w + (size_t)65536 * 1536 * 2);                // 64 MiB
  short* Y      = xbf;                                                   // reuse after GEMM1
  short* wT     = (short*)(w + (size_t)65536 * 1536 * 2 + (size_t)65536 * 512 * 2);
  short* projT  = wT + 1536 * 512;

  k_cast_bf16<<<16384, 256, 0, stream>>>(x, xbf, 33554432 / 8);
  k_transpose_cast<<<dim3(24, 8), 256, 0, stream>>>(qkv_w, wT, 512, 1536);
  k_transpose_cast<<<dim3(8, 8), 256, 0, stream>>>(proj_w, projT, 512, 512);
  k_gemm256p<2, 6, 512><<<256, 512, 0, stream>>>(xbf, wT, qkv_b, qkv_ws, 1536, 6);
  k_attn<<<dim3(1024, 4), 256, 0, stream>>>(qkv_ws, mask, btab, Y);
  k_gemm256p<1, 2, 512><<<256, 512, 0, stream>>>(Y, projT, proj_b, out, 512, 2);
}

// Round 13
// 334.087 us; speedup vs baseline: 1.1834x; 1.1834x over previous
//
#include <hip/hip_runtime.h>
#include <hip/hip_bf16.h>
#include <stdint.h>

typedef __attribute__((ext_vector_type(4))) float f32x4;
typedef __attribute__((ext_vector_type(8))) short s16x8;

__device__ __forceinline__ short f2bf(float f) {
  union { float f; uint32_t u; } v; v.f = f;
  uint32_t r = v.u + 0x7FFFu + ((v.u >> 16) & 1u);
  return (short)(r >> 16);
}
__device__ __forceinline__ uint32_t pack2bf(float a, float b) {
  return (uint32_t)(uint16_t)f2bf(a) | ((uint32_t)(uint16_t)f2bf(b) << 16);
}

__device__ __forceinline__ void async16(const void* g, void* l) {
  __builtin_amdgcn_global_load_lds(
      (const __attribute__((address_space(1))) void*)g,
      (__attribute__((address_space(3))) void*)l, 16, 0, 0);
}

// -------- LDS-tiled transpose+cast: out[n][k] = bf16(in[k][n]) --------
__global__ __launch_bounds__(256) void k_transpose_cast(const float* __restrict__ in,
                                                        short* __restrict__ out,
                                                        int K, int N) {
  __shared__ float tile[64][65];
  const int bx = blockIdx.x;
  const int by = blockIdx.y;
  const int tx = threadIdx.x & 63, ty = threadIdx.x >> 6;
#pragma unroll
  for (int r = ty; r < 64; r += 4)
    tile[r][tx] = in[(size_t)(by * 64 + r) * N + bx * 64 + tx];
  __syncthreads();
#pragma unroll
  for (int r = ty; r < 64; r += 4)
    out[(size_t)(bx * 64 + r) * K + by * 64 + tx] = f2bf(tile[tx][r]);
}

// ============== FUSED cast + QKV-GEMM + window attention ==============
// 1 block = 1 window (64 rows). 4 waves; each wave does 4 heads sequentially:
//   mini-GEMM 64x96 (K=512): A = x_lds (staged fp32->bf16, chunk-swizzled),
//   B = wT rows streamed from L2 (1-deep prefetch), swapped-operand MFMA ->
//   lane holds 4 consecutive d -> packed epilogue into q/k/v LDS [64][40];
//   then proven v3 attention (swapped QK^T, in-reg softmax, P overlay on q+k).
__global__ __launch_bounds__(256, 1) void k_fused(const float* __restrict__ x,
                                                  const short* __restrict__ wT,
                                                  const float* __restrict__ qkvb,
                                                  const float* __restrict__ mask,
                                                  const float* __restrict__ btab,
                                                  short* __restrict__ Y) {
  __shared__ __align__(16) short x_lds[64 * 512];       // 64 KB
  __shared__ __align__(16) float mask_lds[64 * 64];     // 16 KB  [n][m^((n&7)<<2)]
  __shared__ float bias_all[16][128];                   // 8 KB   per-head diag
  __shared__ float qb_lds[1536];                        // 6 KB
  __shared__ __align__(16) short qk_lds[4][2][64][40];  // 40 KB  q,k (P overlays)
  __shared__ __align__(16) short v_lds[4][64][40];      // 20 KB

  const int t = threadIdx.x, wv = t >> 6, ln = t & 63;
  const int w = blockIdx.x;
  const int hi = ln >> 4, lo = ln & 15;

  // ---- stage x window: fp32 -> bf16, chunk-swizzled (slot = cs ^ (row&7)) ----
  const float* xw = x + (size_t)w * 32768;
#pragma unroll
  for (int u = 0; u < 16; ++u) {
    int c = u * 256 + t;
    int row = c >> 6, cs = c & 63;
    const float* src = xw + row * 512 + cs * 8;
    float4 f0 = *(const float4*)src;
    float4 f1 = *(const float4*)(src + 4);
    s16x8 o;
    o[0] = f2bf(f0.x); o[1] = f2bf(f0.y); o[2] = f2bf(f0.z); o[3] = f2bf(f0.w);
    o[4] = f2bf(f1.x); o[5] = f2bf(f1.y); o[6] = f2bf(f1.z); o[7] = f2bf(f1.w);
    *(s16x8*)&x_lds[row * 512 + ((cs ^ (row & 7)) << 3)] = o;
  }
  // ---- stage mask (XOR-swizzled) ----
  const float4* mk = (const float4*)(mask + (size_t)(w & 63) * 4096);
#pragma unroll
  for (int u = 0; u < 4; ++u) {
    int idx = t + 256 * u;
    int row = idx >> 4, c4 = (idx & 15) * 4;
    *(float4*)&mask_lds[row * 64 + (c4 ^ ((row & 7) << 2))] = mk[idx];
  }
  // ---- stage bias tables ----
#pragma unroll
  for (int u = 0; u < 8; ++u) {
    int idx = t + 256 * u;
    if (idx < 2032) bias_all[idx & 15][idx >> 4] = btab[idx];
  }
#pragma unroll
  for (int u = 0; u < 6; ++u) qb_lds[t + 256 * u] = qkvb[t + 256 * u];
  __syncthreads();

  short* q0 = &qk_lds[wv][0][0][0];
  short* k0 = &qk_lds[wv][1][0][0];
  short* vv = &v_lds[wv][0][0];
  short* P  = q0;  // [64][72] overlay on q+k (10240 B >= 9216 B)

  const float scale = 0.17677669529663687f;
  const int rr_base = (w >> 4);

  for (int hh = 0; hh < 4; ++hh) {
    const int h = wv * 4 + hh;

    // ======== mini-GEMM: qkv[64][96] for head h ========
    const short* wbase[6];
#pragma unroll
    for (int f = 0; f < 6; ++f) {
      int sel = f >> 1, njj = f & 1;
      wbase[f] = wT + (size_t)(sel * 512 + h * 32 + njj * 16 + lo) * 512 + hi * 8;
    }
    f32x4 acc[4][6] = {};
    s16x8 wfA[6], wfB[6];
#pragma unroll
    for (int f = 0; f < 6; ++f) wfA[f] = *(const s16x8*)(wbase[f]);

#pragma unroll
    for (int kt2 = 0; kt2 < 8; ++kt2) {
      {
        const int kt = 2 * kt2;
#pragma unroll
        for (int f = 0; f < 6; ++f) wfB[f] = *(const s16x8*)(wbase[f] + (kt + 1) * 32);
        s16x8 xf[4];
#pragma unroll
        for (int mi = 0; mi < 4; ++mi)
          xf[mi] = *(const s16x8*)&x_lds[(16 * mi + lo) * 512 + (((kt * 4 + hi) ^ (lo & 7)) << 3)];
#pragma unroll
        for (int mi = 0; mi < 4; ++mi)
#pragma unroll
          for (int f = 0; f < 6; ++f)
            acc[mi][f] = __builtin_amdgcn_mfma_f32_16x16x32_bf16(wfA[f], xf[mi], acc[mi][f], 0, 0, 0);
      }
      {
        const int kt = 2 * kt2 + 1;
        if (kt2 < 7) {
#pragma unroll
          for (int f = 0; f < 6; ++f) wfA[f] = *(const s16x8*)(wbase[f] + (kt + 1) * 32);
        }
        s16x8 xf[4];
#pragma unroll
        for (int mi = 0; mi < 4; ++mi)
          xf[mi] = *(const s16x8*)&x_lds[(16 * mi + lo) * 512 + (((kt * 4 + hi) ^ (lo & 7)) << 3)];
#pragma unroll
        for (int mi = 0; mi < 4; ++mi)
#pragma unroll
          for (int f = 0; f < 6; ++f)
            acc[mi][f] = __builtin_amdgcn_mfma_f32_16x16x32_bf16(wfB[f], xf[mi], acc[mi][f], 0, 0, 0);
      }
    }

    // ---- epilogue: +bias (q also *scale), packed writes into q/k/v LDS ----
#pragma unroll
    for (int f = 0; f < 6; ++f) {
      int sel = f >> 1, njj = f & 1;
      float4 b4 = *(const float4*)&qb_lds[sel * 512 + h * 32 + njj * 16 + 4 * hi];
      short* dst = (sel == 0) ? q0 : (sel == 1) ? k0 : vv;
#pragma unroll
      for (int mi = 0; mi < 4; ++mi) {
        float v0 = acc[mi][f][0] + b4.x, v1 = acc[mi][f][1] + b4.y;
        float v2 = acc[mi][f][2] + b4.z, v3 = acc[mi][f][3] + b4.w;
        if (sel == 0) { v0 *= scale; v1 *= scale; v2 *= scale; v3 *= scale; }
        uint2 pk;
        pk.x = pack2bf(v0, v1);
        pk.y = pack2bf(v2, v3);
        *(uint2*)&dst[(16 * mi + lo) * 40 + njj * 16 + 4 * hi] = pk;
      }
    }
    asm volatile("s_waitcnt lgkmcnt(0)" ::: "memory");

    // ======== attention (proven v3 structure) ========
    s16x8 qf[4], kf[4];
#pragma unroll
    for (int i = 0; i < 4; ++i) {
      qf[i] = *(const s16x8*)&q0[(16 * i + lo) * 40 + hi * 8];
      kf[i] = *(const s16x8*)&k0[(16 * i + lo) * 40 + hi * 8];
    }
    f32x4 s2[4][4] = {};
#pragma unroll
    for (int j = 0; j < 4; ++j)
#pragma unroll
      for (int i = 0; i < 4; ++i)
        s2[j][i] = __builtin_amdgcn_mfma_f32_16x16x32_bf16(kf[j], qf[i], s2[j][i], 0, 0, 0);

#pragma unroll
    for (int i = 0; i < 4; ++i) {
      const int n = 16 * i + lo;
      const int msw = (n & 7) << 2;
      float xv[16];
      float vmax = -1e30f;
#pragma unroll
      for (int j = 0; j < 4; ++j)
#pragma unroll
        for (int r = 0; r < 4; ++r) {
          int m = 16 * j + 4 * hi + r;
          float xx = s2[j][i][r] + bias_all[h][n - m + 63] + mask_lds[n * 64 + (m ^ msw)];
          xv[j * 4 + r] = xx;
          vmax = fmaxf(vmax, xx);
        }
      vmax = fmaxf(vmax, __shfl_xor(vmax, 16, 64));
      vmax = fmaxf(vmax, __shfl_xor(vmax, 32, 64));
      float sum = 0.f;
#pragma unroll
      for (int u = 0; u < 16; ++u) {
        xv[u] = __expf(xv[u] - vmax);
        sum += xv[u];
      }
      sum += __shfl_xor(sum, 16, 64);
      sum += __shfl_xor(sum, 32, 64);
      float rsv = 1.0f / sum;
#pragma unroll
      for (int j = 0; j < 4; ++j)
#pragma unroll
        for (int rp = 0; rp < 2; ++rp)
          *(uint32_t*)&P[n * 72 + 16 * j + 4 * hi + rp * 2] =
              pack2bf(xv[j * 4 + rp * 2] * rsv, xv[j * 4 + rp * 2 + 1] * rsv);
    }
    asm volatile("s_waitcnt lgkmcnt(0)" ::: "memory");

    f32x4 o2[2][4] = {};
#pragma unroll
    for (int kk = 0; kk < 2; ++kk) {
      s16x8 pa[4];
#pragma unroll
      for (int i2 = 0; i2 < 4; ++i2)
        pa[i2] = *(const s16x8*)&P[(16 * i2 + lo) * 72 + kk * 32 + hi * 8];
#pragma unroll
      for (int j2 = 0; j2 < 2; ++j2) {
        s16x8 vf;
#pragma unroll
        for (int jj = 0; jj < 8; ++jj)
          vf[jj] = vv[(kk * 32 + hi * 8 + jj) * 40 + 16 * j2 + lo];
#pragma unroll
        for (int i2 = 0; i2 < 4; ++i2)
          o2[j2][i2] = __builtin_amdgcn_mfma_f32_16x16x32_bf16(vf, pa[i2], o2[j2][i2], 0, 0, 0);
      }
    }

    const int rr = h * 64 + rr_base;
#pragma unroll
    for (int i2 = 0; i2 < 4; ++i2) {
      int ss = (w & 15) * 4 + i2;
      short* yr = Y + ((size_t)rr * 64 + ss) * 512 + lo * 32 + 4 * hi;
#pragma unroll
      for (int j2 = 0; j2 < 2; ++j2) {
        uint2 pk;
        pk.x = pack2bf(o2[j2][i2][0], o2[j2][i2][1]);
        pk.y = pack2bf(o2[j2][i2][2], o2[j2][i2][3]);
        *(uint2*)(yr + 16 * j2) = pk;
      }
    }
  }
}

// ===== persistent 256x256 8-phase bf16 GEMM (round-7/11 proven) =====
#define TILE_SH 16384

template <int OUTMODE, int NBN, int KK>
__global__ __launch_bounds__(512, 2) void k_gemm256p(const short* __restrict__ A,
                                                     const short* __restrict__ Bw,
                                                     const float* __restrict__ bias,
                                                     void* __restrict__ C,
                                                     int N, int nrounds) {
  __shared__ short lds[2 * 2 * TILE_SH];
  const int t = threadIdx.x;
  const int w = t >> 6, l = t & 63;
  const int wm = w >> 2, wn = w & 3;
  const int swz = (((int)blockIdx.x & 7) << 5) + ((int)blockIdx.x >> 3);

  const int NT = KK >> 6;
  const int NS = nrounds * NT;

  auto stage = [&](const short* __restrict__ G, int row0, int kt, short* dst) {
#pragma unroll
    for (int L = 0; L < 2; ++L) {
      int cw = L * 512 + (t & ~63);
      int c = cw + l;
      int r = c >> 3, s = c & 7;
      async16(G + (size_t)(row0 + r) * KK + kt + ((s ^ (r & 7)) << 3), dst + cw * 8);
    }
  };
  auto issueA = [&](int step, int bmv, int hf) {
    int kt = step & 7;
    stage(A, bmv * 256 + hf * 128, kt * 64, lds + (kt & 1) * 32768 + hf * 8192);
  };
  auto issueB = [&](int step, int bnv, int hf) {
    int kt = step & 7;
    stage(Bw, bnv * 256 + hf * 128, kt * 64, lds + (kt & 1) * 32768 + TILE_SH + hf * 8192);
  };

  const int g = l >> 4, v = l & 7;
  int ofsA[2], ofsB[2];
#pragma unroll
  for (int ks = 0; ks < 2; ++ks) {
    ofsA[ks] = (wm * 128 + (l & 15)) * 64 + (((ks * 4 + g) ^ v) << 3);
    ofsB[ks] = (wn * 64 + (l & 15)) * 64 + (((ks * 4 + g) ^ v) << 3);
  }

  f32x4 acc[8][4] = {};
  s16x8 bfr[4][2];

  {
    const int bm0 = swz / NBN, bn0 = swz % NBN;
    issueB(0, bn0, 0); issueB(0, bn0, 1);
    issueA(0, bm0, 0); issueA(0, bm0, 1);
    issueB(1, bn0, 0); issueB(1, bn0, 1);
  }
  asm volatile("s_waitcnt vmcnt(4)" ::: "memory");
  __builtin_amdgcn_s_barrier();

#define PHASE(AI0, STAGE_STMT, TAIL_STMT)                                                                      \
  {                                                                                                            \
    s16x8 a00 = *(const s16x8*)(Ab + ofsA[0] + (AI0) * 1024);                                                  \
    s16x8 a01 = *(const s16x8*)(Ab + ofsA[1] + (AI0) * 1024);                                                  \
    s16x8 a10 = *(const s16x8*)(Ab + ofsA[0] + ((AI0) + 1) * 1024);                                            \
    s16x8 a11 = *(const s16x8*)(Ab + ofsA[1] + ((AI0) + 1) * 1024);                                            \
    STAGE_STMT;                                                                                                \
    __builtin_amdgcn_s_barrier();                                                                              \
    asm volatile("s_waitcnt lgkmcnt(0)" ::: "memory");                                                         \
    __builtin_amdgcn_s_setprio(1);                                                                             \
    _Pragma("unroll")                                                                                          \
    for (int nj = 0; nj < 4; ++nj) {                                                                           \
      acc[(AI0)][nj] = __builtin_amdgcn_mfma_f32_16x16x32_bf16(a00, bfr[nj][0], acc[(AI0)][nj], 0, 0, 0);      \
      acc[(AI0)][nj] = __builtin_amdgcn_mfma_f32_16x16x32_bf16(a01, bfr[nj][1], acc[(AI0)][nj], 0, 0, 0);      \
      acc[(AI0) + 1][nj] = __builtin_amdgcn_mfma_f32_16x16x32_bf16(a10, bfr[nj][0], acc[(AI0) + 1][nj], 0, 0, 0); \
      acc[(AI0) + 1][nj] = __builtin_amdgcn_mfma_f32_16x16x32_bf16(a11, bfr[nj][1], acc[(AI0) + 1][nj], 0, 0, 0); \
    }                                                                                                          \
    __builtin_amdgcn_s_setprio(0);                                                                             \
    TAIL_STMT;                                                                                                 \
    __builtin_amdgcn_s_barrier();                                                                              \
  }

  for (int j = 0; j < nrounds; ++j) {
    const int tauc = swz + (j << 8);
    const int bmc = tauc / NBN, bnc = tauc % NBN;
    for (int T = 0; T < NT; ++T) {
      const int s = (j << 3) + T;
      const int s1 = s + 1, s2 = s + 2;
      const int tau1 = swz + ((s1 >> 3) << 8);
      const int tau2 = swz + ((s2 >> 3) << 8);
      const int bm1 = tau1 / NBN;
      const int bn2 = tau2 % NBN;
      const short* Ab = lds + (T & 1) * 32768;
      const short* Bb = Ab + TILE_SH;
#pragma unroll
      for (int nj = 0; nj < 4; ++nj)
#pragma unroll
        for (int ks = 0; ks < 2; ++ks)
          bfr[nj][ks] = *(const s16x8*)(Bb + ofsB[ks] + nj * 1024);

      PHASE(0, if (s1 < NS) issueA(s1, bm1, 0), );
      PHASE(2, if (s1 < NS) issueA(s1, bm1, 1), );
      PHASE(4, if (s2 < NS) issueB(s2, bn2, 0), );
      PHASE(6, if (s2 < NS) issueB(s2, bn2, 1),
            if (s2 < NS) { asm volatile("s_waitcnt vmcnt(4)" ::: "memory"); }
            else if (s1 < NS) { asm volatile("s_waitcnt vmcnt(0)" ::: "memory"); });
    }

#pragma unroll
    for (int ai = 0; ai < 8; ++ai)
#pragma unroll
      for (int nj = 0; nj < 4; ++nj) {
        int col = bnc * 256 + wn * 64 + nj * 16 + (l & 15);
        float bv = bias[col];
#pragma unroll
        for (int r = 0; r < 4; ++r) {
          int row = bmc * 256 + wm * 128 + ai * 16 + (l >> 4) * 4 + r;
          float vv = acc[ai][nj][r] + bv;
          if (OUTMODE == 1) {
            ((float*)C)[(size_t)row * N + col] = vv;
          } else {
            ((short*)C)[(size_t)row * N + col] = f2bf(vv);
          }
        }
      }
#pragma unroll
    for (int ai = 0; ai < 8; ++ai)
#pragma unroll
      for (int nj = 0; nj < 4; ++nj)
        acc[ai][nj] = (f32x4){0.f, 0.f, 0.f, 0.f};
  }
#undef PHASE
}

extern "C" void kernel_launch(void* const* d_in, const int* in_sizes, int n_in,
                              void* d_out, int out_size, void* d_ws, size_t ws_size,
                              hipStream_t stream) {
  const float* x      = (const float*)d_in[0];
  const float* mask   = (const float*)d_in[1];
  const float* qkv_w  = (const float*)d_in[2];
  const float* qkv_b  = (const float*)d_in[3];
  const float* proj_w = (const float*)d_in[4];
  const float* proj_b = (const float*)d_in[5];
  const float* btab   = (const float*)d_in[6];
  float* out = (float*)d_out;

  char* w = (char*)d_ws;
  short* Y     = (short*)w;                                  // 64 MiB
  short* wT    = (short*)(w + (size_t)65536 * 512 * 2);
  short* projT = wT + 1536 * 512;

  k_transpose_cast<<<dim3(24, 8), 256, 0, stream>>>(qkv_w, wT, 512, 1536);
  k_transpose_cast<<<dim3(8, 8), 256, 0, stream>>>(proj_w, projT, 512, 512);
  k_fused<<<1024, 256, 0, stream>>>(x, wT, qkv_b, mask, btab, Y);
  k_gemm256p<1, 2, 512><<<256, 512, 0, stream>>>(Y, projT, proj_b, out, 512, 2);
}